// Round 1
// 2745.161 us; speedup vs baseline: 2.0146x; 2.0146x over previous
//
#include <hip/hip_runtime.h>

// ---------------------------------------------------------------------------
// GPT forward (B=2,T=1024,C=768,H=12,hd=64,L=4,V=50304,DINT=64) on gfx950.
// entmax(alpha=1+1e-6) over [raw,0] == sigmoid(raw) to ~1e-5 (see analysis).
// All GEMMs: bf16 MFMA 16x16x32, f32 accumulate. Residuals/masks/softmax f32.
// ---------------------------------------------------------------------------

using f32x4  = __attribute__((ext_vector_type(4))) float;
using bf16x8 = __attribute__((ext_vector_type(8))) __bf16;
typedef unsigned short u16;
typedef unsigned int   u32;

#define B_  2
#define T_  1024
#define C_  768
#define H_  12
#define HD_ 64
#define L_  4
#define V_  50304

__device__ __forceinline__ u16 f2bf(float f){
  u32 u = __float_as_uint(f);
  u += 0x7fffu + ((u >> 16) & 1u);       // RNE to bf16
  return (u16)(u >> 16);
}

// -------------------------- weight / tensor converts -----------------------
__global__ __launch_bounds__(256) void f2bf_vec(const float4* __restrict__ src,
                                                ushort4* __restrict__ dst){
  long i = (long)blockIdx.x * 256 + threadIdx.x;
  float4 v = src[i];
  ushort4 o;
  o.x = f2bf(v.x); o.y = f2bf(v.y); o.z = f2bf(v.z); o.w = f2bf(v.w);
  dst[i] = o;
}

// interleave qint_w / kint_w -> wint[l][128][768] bf16 (rows 0-63 q, 64-127 k)
__global__ __launch_bounds__(256) void build_wint(const float* __restrict__ qint_w,
                                                  const float* __restrict__ kint_w,
                                                  u16* __restrict__ wint){
  long i = (long)blockIdx.x * 256 + threadIdx.x;   // < 4*128*768
  int c  = (int)(i % 768);
  long r = i / 768;
  int rr = (int)(r & 127);
  int l  = (int)(r >> 7);
  const float* src = (rr < 64) ? qint_w : kint_w;
  wint[i] = f2bf(src[((long)l * 64 + (rr & 63)) * 768 + c]);
}

// ------------------------------- embedding ---------------------------------
__global__ __launch_bounds__(256) void embed_kernel(const float* __restrict__ wte,
                                                    const float* __restrict__ wpe,
                                                    const int* __restrict__ idx,
                                                    float* __restrict__ x){
  int row = blockIdx.x;              // b*T + t
  int t   = row & (T_ - 1);
  int id  = idx[row];
  const float* ws = wte + (long)id * C_;
  const float* ps = wpe + (long)t  * C_;
  float* xr = x + (long)row * C_;
  for (int c = threadIdx.x; c < C_; c += 256) xr[c] = ws[c] + ps[c];
}

// ------------------------------- layernorm ---------------------------------
__global__ __launch_bounds__(256) void layernorm_bf16(const float* __restrict__ x,
                                                      const float* __restrict__ w,
                                                      const float* __restrict__ bsh,
                                                      u16* __restrict__ out){
  int row = blockIdx.x;
  const float* xr = x + (long)row * C_;
  int tid = threadIdx.x;
  float v[3], s = 0.f, ss = 0.f;
  #pragma unroll
  for (int k = 0; k < 3; ++k){
    float t = xr[tid + k * 256];
    v[k] = t; s += t; ss += t * t;
  }
  #pragma unroll
  for (int off = 1; off < 64; off <<= 1){
    s  += __shfl_xor(s,  off, 64);
    ss += __shfl_xor(ss, off, 64);
  }
  __shared__ float red[8];
  int wid = tid >> 6, lane = tid & 63;
  if (lane == 0){ red[wid] = s; red[4 + wid] = ss; }
  __syncthreads();
  s  = red[0] + red[1] + red[2] + red[3];
  ss = red[4] + red[5] + red[6] + red[7];
  float mu   = s * (1.f / C_);
  float var  = ss * (1.f / C_) - mu * mu;
  float rstd = rsqrtf(var + 1e-5f);
  u16* outr = out + (long)row * C_;
  #pragma unroll
  for (int k = 0; k < 3; ++k){
    int c = tid + k * 256;
    outr[c] = f2bf((v[k] - mu) * rstd * w[c] + bsh[c]);
  }
}

// ------------------------- bf16 NT GEMM (MFMA) -----------------------------
// C[m,n] = alpha * sum_k A[m,k]*B[n,k]  (+bias[n]) (+gelu) (+addsrc[m,n])
template<int BM, int BN, int WM, int WN, bool GELU>
__global__ __launch_bounds__(256) void gemm_nt(
    const u16* __restrict__ A, const u16* __restrict__ B, float* __restrict__ C,
    const float* __restrict__ bias, const float* __restrict__ addsrc,
    int K, int lda, int ldb, int ldc,
    long batchA, long batchB, long batchC, float alpha)
{
  constexpr int BK  = 32;
  constexpr int LDS = BK + 8;     // pad: 80B row stride -> 2-way bank alias (free)
  __shared__ __align__(16) u16 As[BM * LDS];
  __shared__ __align__(16) u16 Bs[BN * LDS];
  const int z = blockIdx.z;
  A += (long)z * batchA;
  B += (long)z * batchB;
  float* Cz = C + (long)z * batchC;
  const float* addz = addsrc ? addsrc + (long)z * batchC : nullptr;
  const int n0 = blockIdx.x * BN, m0 = blockIdx.y * BM;
  const int tid = threadIdx.x, lane = tid & 63, wid = tid >> 6;
  const int l15 = lane & 15, quad = lane >> 4;
  constexpr int WCOLS = BN / WN;
  const int wrow = wid / WCOLS, wcol = wid % WCOLS;
  constexpr int FM = WM / 16, FN = WN / 16;
  f32x4 acc[FM][FN] = {};
  const int ktiles = K / BK;
  for (int kt = 0; kt < ktiles; ++kt){
    constexpr int CHA = BM * BK / 8;
    for (int i = tid; i < CHA; i += 256){
      int row = i >> 2, c8 = (i & 3) * 8;
      *(uint4*)&As[row * LDS + c8] =
          *(const uint4*)(A + (long)(m0 + row) * lda + kt * BK + c8);
    }
    constexpr int CHB = BN * BK / 8;
    for (int i = tid; i < CHB; i += 256){
      int row = i >> 2, c8 = (i & 3) * 8;
      *(uint4*)&Bs[row * LDS + c8] =
          *(const uint4*)(B + (long)(n0 + row) * ldb + kt * BK + c8);
    }
    __syncthreads();
    bf16x8 af[FM], bfr[FN];
    #pragma unroll
    for (int fm = 0; fm < FM; ++fm)
      af[fm] = *(const bf16x8*)&As[(wrow * WM + fm * 16 + l15) * LDS + quad * 8];
    #pragma unroll
    for (int fn = 0; fn < FN; ++fn)
      bfr[fn] = *(const bf16x8*)&Bs[(wcol * WN + fn * 16 + l15) * LDS + quad * 8];
    #pragma unroll
    for (int fm = 0; fm < FM; ++fm)
      #pragma unroll
      for (int fn = 0; fn < FN; ++fn)
        acc[fm][fn] = __builtin_amdgcn_mfma_f32_16x16x32_bf16(af[fm], bfr[fn],
                                                              acc[fm][fn], 0, 0, 0);
    __syncthreads();
  }
  #pragma unroll
  for (int fm = 0; fm < FM; ++fm){
    const int rowb = m0 + wrow * WM + fm * 16 + quad * 4;
    #pragma unroll
    for (int fn = 0; fn < FN; ++fn){
      const int col = n0 + wcol * WN + fn * 16 + l15;
      const float bv = bias ? bias[col] : 0.f;
      #pragma unroll
      for (int r = 0; r < 4; ++r){
        float v = acc[fm][fn][r] * alpha + bv;
        if (GELU)
          v = 0.5f * v * (1.f + tanhf(0.7978845608028654f * (v + 0.044715f * v * v * v)));
        const long off = (long)(rowb + r) * ldc + col;
        if (addz) v += addz[off];
        Cz[off] = v;
      }
    }
  }
}

// ---------------- mask: logsigmoid + column cumsum + layer accum -----------
// Block-parallel inclusive scan over queries.
// Grid: (B*T)/CT blocks of 256 threads. CT=8 columns/block; 32 row-groups of
// 32 rows each. Phase 1: per-thread logsigmoid of its 32 rows into REGISTERS
// (static indices, full unroll) + local sum; LDS [32][8] group sums; prefix
// offset per column. Phase 2: replay registers, emit running sum into Macc.
__global__ __launch_bounds__(256) void lp_cumsum(const float* __restrict__ raw,
                                                 const float* __restrict__ int_bias,
                                                 int layer, float* __restrict__ Macc){
  constexpr int CT  = 8;                     // columns per block
  constexpr int RG  = 32;                    // row groups
  constexpr int RPT = T_ / RG;               // rows per thread = 32
  const int tid = threadIdx.x;
  const int c   = tid & (CT - 1);            // column within block
  const int g   = tid >> 3;                  // row group 0..31
  const int gc  = blockIdx.x * CT + c;       // global column 0..2047
  const int b   = gc >> 10;
  const int k   = gc & (T_ - 1);
  const float bias = int_bias[layer];
  const float* rb = raw  + (long)b * T_ * T_;
  float*       Mb = Macc + (long)b * T_ * T_;
  const int q0 = g * RPT;

  float lp[RPT];
  float s = 0.f;
  #pragma unroll
  for (int i = 0; i < RPT; ++i){
    int q = q0 + i;
    float z = rb[(long)q * T_ + k] + bias;
    float v = 0.f;
    if (q > k) v = (z >= -30.f) ? -log1pf(__expf(-z)) : z;
    lp[i] = v;
    s += v;
  }
  __shared__ float sums[RG][CT];
  sums[g][c] = s;
  __syncthreads();
  float run = 0.f;
  for (int g2 = 0; g2 < g; ++g2) run += sums[g2][c];
  #pragma unroll
  for (int i = 0; i < RPT; ++i){
    int q = q0 + i;
    run += lp[i];
    long off = (long)q * T_ + k;
    if (layer == 0) Mb[off] = run;
    else            Mb[off] += run;
  }
}

// -------------- reshape qkv -> head-major q,k (bf16) and v^T (bf16) --------
__global__ __launch_bounds__(256) void reshape_qkv(const float* __restrict__ qkv,
                                                   u16* __restrict__ qb,
                                                   u16* __restrict__ kb,
                                                   u16* __restrict__ vT){
  int row = blockIdx.x;               // b*T + t
  int b = row >> 10, t = row & (T_ - 1);
  const float* src = qkv + (long)row * 2304;
  for (int i = threadIdx.x; i < C_; i += 256){
    int h = i >> 6, d = i & 63;
    long bh = (long)b * H_ + h;
    qb[(bh * T_ + t) * HD_ + d] = f2bf(src[i]);
    kb[(bh * T_ + t) * HD_ + d] = f2bf(src[C_ + i]);
    vT[(bh * HD_ + d) * T_ + t] = f2bf(src[2 * C_ + i]);
  }
}

// --------------------- fused flash attention (bf16 MFMA) -------------------
// grid (T/64, B*H), block 256 (4 waves); wave w owns 16 queries.
__global__ __launch_bounds__(256) void attn_kernel(const u16* __restrict__ qb,
                                                   const u16* __restrict__ kb,
                                                   const u16* __restrict__ vT,
                                                   const float* __restrict__ Macc,
                                                   u16* __restrict__ ybf){
  __shared__ __align__(16) u16 P[4][16 * 72];    // per-wave P tile, padded
  const int qt = blockIdx.x, bh = blockIdx.y;
  const int b = bh / H_, h = bh % H_;
  const int tid = threadIdx.x, wid = tid >> 6, lane = tid & 63;
  const int l15 = lane & 15, quad = lane >> 4;
  const int qbase = qt * 64 + wid * 16;

  const u16* qrow = qb + ((long)bh * T_ + qbase + l15) * HD_;
  bf16x8 aq0 = *(const bf16x8*)(qrow + quad * 8);
  bf16x8 aq1 = *(const bf16x8*)(qrow + 32 + quad * 8);

  float mrow[4], lrow[4];
  f32x4 oacc[4] = {};
  #pragma unroll
  for (int r = 0; r < 4; ++r){ mrow[r] = -1e30f; lrow[r] = 0.f; }

  const float* Mb = Macc + (long)b * T_ * T_;
  const int ntiles = qt + 1;
  for (int kt = 0; kt < ntiles; ++kt){
    // S = Q K^T
    f32x4 s[4];
    #pragma unroll
    for (int fn = 0; fn < 4; ++fn){
      const u16* krow = kb + ((long)bh * T_ + kt * 64 + fn * 16 + l15) * HD_;
      bf16x8 bk0 = *(const bf16x8*)(krow + quad * 8);
      bf16x8 bk1 = *(const bf16x8*)(krow + 32 + quad * 8);
      f32x4 t = {};
      t = __builtin_amdgcn_mfma_f32_16x16x32_bf16(aq0, bk0, t, 0, 0, 0);
      t = __builtin_amdgcn_mfma_f32_16x16x32_bf16(aq1, bk1, t, 0, 0, 0);
      s[fn] = t;
    }
    // scale + additive mask + causal
    float pv[4][4], tmax[4];
    #pragma unroll
    for (int r = 0; r < 4; ++r) tmax[r] = -1e30f;
    #pragma unroll
    for (int fn = 0; fn < 4; ++fn){
      int col = kt * 64 + fn * 16 + l15;
      #pragma unroll
      for (int r = 0; r < 4; ++r){
        int row = qbase + quad * 4 + r;
        float v = (col <= row) ? s[fn][r] * 0.125f + Mb[(long)row * T_ + col]
                               : -1e30f;
        pv[fn][r] = v;
        tmax[r] = fmaxf(tmax[r], v);
      }
    }
    #pragma unroll
    for (int r = 0; r < 4; ++r){
      float v = tmax[r];
      v = fmaxf(v, __shfl_xor(v, 1, 16));
      v = fmaxf(v, __shfl_xor(v, 2, 16));
      v = fmaxf(v, __shfl_xor(v, 4, 16));
      v = fmaxf(v, __shfl_xor(v, 8, 16));
      tmax[r] = v;
    }
    float alp[4], rsum[4];
    #pragma unroll
    for (int r = 0; r < 4; ++r){
      float mnew = fmaxf(mrow[r], tmax[r]);
      alp[r] = __expf(mrow[r] - mnew);
      mrow[r] = mnew;
      rsum[r] = 0.f;
    }
    #pragma unroll
    for (int fn = 0; fn < 4; ++fn)
      #pragma unroll
      for (int r = 0; r < 4; ++r){
        float p = __expf(pv[fn][r] - mrow[r]);
        pv[fn][r] = p;
        rsum[r] += p;
      }
    #pragma unroll
    for (int r = 0; r < 4; ++r){
      float v = rsum[r];
      v += __shfl_xor(v, 1, 16);
      v += __shfl_xor(v, 2, 16);
      v += __shfl_xor(v, 4, 16);
      v += __shfl_xor(v, 8, 16);
      lrow[r] = lrow[r] * alp[r] + v;
    }
    // P (C-layout) -> LDS -> A-layout; rescale O
    #pragma unroll
    for (int fn = 0; fn < 4; ++fn)
      #pragma unroll
      for (int r = 0; r < 4; ++r)
        P[wid][(quad * 4 + r) * 72 + fn * 16 + l15] = f2bf(pv[fn][r]);
    #pragma unroll
    for (int fn = 0; fn < 4; ++fn)
      #pragma unroll
      for (int r = 0; r < 4; ++r)
        oacc[fn][r] *= alp[r];
    bf16x8 ap0 = *(const bf16x8*)&P[wid][l15 * 72 + quad * 8];
    bf16x8 ap1 = *(const bf16x8*)&P[wid][l15 * 72 + 32 + quad * 8];
    #pragma unroll
    for (int fn = 0; fn < 4; ++fn){
      const u16* vrow = vT + ((long)bh * HD_ + fn * 16 + l15) * T_ + kt * 64;
      bf16x8 bv0 = *(const bf16x8*)(vrow + quad * 8);
      bf16x8 bv1 = *(const bf16x8*)(vrow + 32 + quad * 8);
      oacc[fn] = __builtin_amdgcn_mfma_f32_16x16x32_bf16(ap0, bv0, oacc[fn], 0, 0, 0);
      oacc[fn] = __builtin_amdgcn_mfma_f32_16x16x32_bf16(ap1, bv1, oacc[fn], 0, 0, 0);
    }
  }
  #pragma unroll
  for (int fn = 0; fn < 4; ++fn)
    #pragma unroll
    for (int r = 0; r < 4; ++r){
      int row = qbase + quad * 4 + r;
      int d   = fn * 16 + l15;
      float o = oacc[fn][r] / lrow[r];
      ybf[((long)b * T_ + row) * C_ + h * HD_ + d] = f2bf(o);
    }
}

// ---------------------------------------------------------------------------
extern "C" void kernel_launch(void* const* d_in, const int* in_sizes, int n_in,
                              void* d_out, int out_size, void* d_ws, size_t ws_size,
                              hipStream_t stream)
{
  (void)in_sizes; (void)n_in; (void)out_size; (void)ws_size;
  const float* wte     = (const float*)d_in[0];
  const float* wpe     = (const float*)d_in[1];
  const float* ln1_w   = (const float*)d_in[2];
  const float* ln1_b   = (const float*)d_in[3];
  const float* attn_w  = (const float*)d_in[4];
  const float* attn_b  = (const float*)d_in[5];
  const float* qint_w  = (const float*)d_in[6];
  const float* kint_w  = (const float*)d_in[7];
  const float* int_bias= (const float*)d_in[8];
  const float* proj_w  = (const float*)d_in[9];
  const float* proj_b  = (const float*)d_in[10];
  const float* ln2_w   = (const float*)d_in[11];
  const float* ln2_b   = (const float*)d_in[12];
  const float* fc_w    = (const float*)d_in[13];
  const float* fc_b    = (const float*)d_in[14];
  const float* fc2_w   = (const float*)d_in[15];
  const float* fc2_b   = (const float*)d_in[16];
  const float* lnf_w   = (const float*)d_in[17];
  const float* lnf_b   = (const float*)d_in[18];
  const int*   idx     = (const int*)d_in[19];
  float* out = (float*)d_out;

  char* p = (char*)d_ws;
  auto alloc = [&](long bytes) -> char* {
    char* r = p; p += (bytes + 255) & ~255L; return r;
  };
  u16*   wte_bf   = (u16*)  alloc((long)V_ * C_ * 2);
  u16*   attnw_bf = (u16*)  alloc((long)L_ * 3 * C_ * C_ * 2);
  u16*   wint_bf  = (u16*)  alloc((long)L_ * 128 * C_ * 2);
  u16*   projw_bf = (u16*)  alloc((long)L_ * C_ * C_ * 2);
  u16*   fcw_bf   = (u16*)  alloc((long)L_ * 4 * C_ * C_ * 2);
  u16*   fc2w_bf  = (u16*)  alloc((long)L_ * C_ * 4 * C_ * 2);
  float* x        = (float*)alloc((long)B_ * T_ * C_ * 4);
  u16*   hbf      = (u16*)  alloc((long)B_ * T_ * C_ * 2);
  float* qkv      = (float*)alloc((long)B_ * T_ * 3 * C_ * 4);
  float* qkint    = (float*)alloc((long)B_ * T_ * 128 * 4);
  u16*   qkintbf  = (u16*)  alloc((long)B_ * T_ * 128 * 2);
  float* raw      = (float*)alloc((long)B_ * T_ * T_ * 4);
  float* Macc     = (float*)alloc((long)B_ * T_ * T_ * 4);
  u16*   qb       = (u16*)  alloc((long)B_ * H_ * T_ * HD_ * 2);
  u16*   kb       = (u16*)  alloc((long)B_ * H_ * T_ * HD_ * 2);
  u16*   vT       = (u16*)  alloc((long)B_ * H_ * T_ * HD_ * 2);
  u16*   ybf      = (u16*)  alloc((long)B_ * T_ * C_ * 2);
  float* ff       = (float*)alloc((long)B_ * T_ * 4 * C_ * 4);
  u16*   ffbf     = (u16*)  alloc((long)B_ * T_ * 4 * C_ * 2);

  auto conv = [&](const float* s, u16* d, long n){
    f2bf_vec<<<(int)(n / 1024), 256, 0, stream>>>((const float4*)s, (ushort4*)d);
  };
  // weights -> bf16 (ws is re-poisoned before every call; must redo each time)
  conv(wte,    wte_bf,   (long)V_ * C_);
  conv(attn_w, attnw_bf, (long)L_ * 3 * C_ * C_);
  conv(proj_w, projw_bf, (long)L_ * C_ * C_);
  conv(fc_w,   fcw_bf,   (long)L_ * 4 * C_ * C_);
  conv(fc2_w,  fc2w_bf,  (long)L_ * C_ * 4 * C_);
  build_wint<<<(L_ * 128 * C_) / 256, 256, 0, stream>>>(qint_w, kint_w, wint_bf);

  embed_kernel<<<B_ * T_, 256, 0, stream>>>(wte, wpe, idx, x);

  const int M = B_ * T_;   // 2048
  for (int l = 0; l < L_; ++l){
    // ln1 -> h
    layernorm_bf16<<<M, 256, 0, stream>>>(x, ln1_w + l * C_, ln1_b + l * C_, hbf);
    // qkv = h @ attn_w^T + b
    gemm_nt<128,128,64,64,false><<<dim3(2304/128, M/128), 256, 0, stream>>>(
        hbf, attnw_bf + (long)l * 3 * C_ * C_, qkv, attn_b + l * 3 * C_, nullptr,
        C_, C_, C_, 3 * C_, 0, 0, 0, 1.f);
    // [q_int | k_int] = h @ wint^T
    gemm_nt<64,64,32,32,false><<<dim3(128/64, M/64), 256, 0, stream>>>(
        hbf, wint_bf + (long)l * 128 * C_, qkint, nullptr, nullptr,
        C_, C_, C_, 128, 0, 0, 0, 1.f);
    conv(qkint, qkintbf, (long)M * 128);
    // raw = q_int @ k_int^T / 8   (batched over B)
    gemm_nt<128,128,64,64,false><<<dim3(T_/128, T_/128, B_), 256, 0, stream>>>(
        qkintbf, qkintbf + 64, raw, nullptr, nullptr,
        64, 128, 128, T_, (long)T_ * 128, (long)T_ * 128, (long)T_ * T_, 0.125f);
    // mask: block-parallel scan of logsigmoid(raw+bias), accum across layers
    lp_cumsum<<<(B_ * T_) / 8, 256, 0, stream>>>(raw, int_bias, l, Macc);
    // attention
    reshape_qkv<<<M, 256, 0, stream>>>(qkv, qb, kb, vT);
    attn_kernel<<<dim3(T_/64, B_ * H_), 256, 0, stream>>>(qb, kb, vT, Macc, ybf);
    // x += y @ proj_w^T + b
    gemm_nt<128,128,64,64,false><<<dim3(C_/128, M/128), 256, 0, stream>>>(
        ybf, projw_bf + (long)l * C_ * C_, x, proj_b + l * C_, x,
        C_, C_, C_, C_, 0, 0, 0, 1.f);
    // ln2 -> h2
    layernorm_bf16<<<M, 256, 0, stream>>>(x, ln2_w + l * C_, ln2_b + l * C_, hbf);
    // ff = gelu(h2 @ fc_w^T + b)
    gemm_nt<128,128,64,64,true><<<dim3(4*C_/128, M/128), 256, 0, stream>>>(
        hbf, fcw_bf + (long)l * 4 * C_ * C_, ff, fc_b + l * 4 * C_, nullptr,
        C_, C_, C_, 4 * C_, 0, 0, 0, 1.f);
    conv(ff, ffbf, (long)M * 4 * C_);
    // x += ff @ fc2_w^T + b
    gemm_nt<128,128,64,64,false><<<dim3(C_/128, M/128), 256, 0, stream>>>(
        ffbf, fc2w_bf + (long)l * C_ * 4 * C_, x, fc2_b + l * C_, x,
        4 * C_, 4 * C_, 4 * C_, C_, 0, 0, 0, 1.f);
  }
  // final LN + weight-tied lm_head
  layernorm_bf16<<<M, 256, 0, stream>>>(x, lnf_w, lnf_b, hbf);
  gemm_nt<128,128,64,64,false><<<dim3(V_/128, M/128), 256, 0, stream>>>(
      hbf, wte_bf, out, nullptr, nullptr,
      C_, C_, C_, V_, 0, 0, 0, 1.f);
}

// Round 2
// 2297.418 us; speedup vs baseline: 2.4072x; 1.1949x over previous
//
#include <hip/hip_runtime.h>

// ---------------------------------------------------------------------------
// GPT forward (B=2,T=1024,C=768,H=12,hd=64,L=4,V=50304,DINT=64) on gfx950.
// entmax(alpha=1+1e-6) over [raw,0] == sigmoid(raw) to ~1e-5 (see analysis).
// All GEMMs: bf16 MFMA 16x16x32, f32 accumulate. Residuals/masks/softmax f32.
// GEMM staging: global_load_lds dwordx4 (m97 structure) + XCD-chunked remap.
// ---------------------------------------------------------------------------

using f32x4  = __attribute__((ext_vector_type(4))) float;
using bf16x8 = __attribute__((ext_vector_type(8))) __bf16;
typedef unsigned short u16;
typedef unsigned int   u32;

#define B_  2
#define T_  1024
#define C_  768
#define H_  12
#define HD_ 64
#define L_  4
#define V_  50304

__device__ __forceinline__ u16 f2bf(float f){
  u32 u = __float_as_uint(f);
  u += 0x7fffu + ((u >> 16) & 1u);       // RNE to bf16
  return (u16)(u >> 16);
}

// async global->LDS, 16 bytes per lane. ldsbase must be wave-uniform;
// HW writes ldsbase + lane*16. gsrc is per-lane.
__device__ __forceinline__ void gld_lds16(const u16* gsrc, u16* ldsbase){
  __builtin_amdgcn_global_load_lds(
      (const __attribute__((address_space(1))) void*)gsrc,
      (__attribute__((address_space(3))) void*)ldsbase, 16, 0, 0);
}

// -------------------------- weight / tensor converts -----------------------
__global__ __launch_bounds__(256) void f2bf_vec(const float4* __restrict__ src,
                                                ushort4* __restrict__ dst){
  long i = (long)blockIdx.x * 256 + threadIdx.x;
  float4 v = src[i];
  ushort4 o;
  o.x = f2bf(v.x); o.y = f2bf(v.y); o.z = f2bf(v.z); o.w = f2bf(v.w);
  dst[i] = o;
}

// interleave qint_w / kint_w -> wint[l][128][768] bf16 (rows 0-63 q, 64-127 k)
__global__ __launch_bounds__(256) void build_wint(const float* __restrict__ qint_w,
                                                  const float* __restrict__ kint_w,
                                                  u16* __restrict__ wint){
  long i = (long)blockIdx.x * 256 + threadIdx.x;   // < 4*128*768
  int c  = (int)(i % 768);
  long r = i / 768;
  int rr = (int)(r & 127);
  int l  = (int)(r >> 7);
  const float* src = (rr < 64) ? qint_w : kint_w;
  wint[i] = f2bf(src[((long)l * 64 + (rr & 63)) * 768 + c]);
}

// ------------------------------- embedding ---------------------------------
__global__ __launch_bounds__(256) void embed_kernel(const float* __restrict__ wte,
                                                    const float* __restrict__ wpe,
                                                    const int* __restrict__ idx,
                                                    float* __restrict__ x){
  int row = blockIdx.x;              // b*T + t
  int t   = row & (T_ - 1);
  int id  = idx[row];
  const float* ws = wte + (long)id * C_;
  const float* ps = wpe + (long)t  * C_;
  float* xr = x + (long)row * C_;
  for (int c = threadIdx.x; c < C_; c += 256) xr[c] = ws[c] + ps[c];
}

// ------------------------------- layernorm ---------------------------------
__global__ __launch_bounds__(256) void layernorm_bf16(const float* __restrict__ x,
                                                      const float* __restrict__ w,
                                                      const float* __restrict__ bsh,
                                                      u16* __restrict__ out){
  int row = blockIdx.x;
  const float* xr = x + (long)row * C_;
  int tid = threadIdx.x;
  float v[3], s = 0.f, ss = 0.f;
  #pragma unroll
  for (int k = 0; k < 3; ++k){
    float t = xr[tid + k * 256];
    v[k] = t; s += t; ss += t * t;
  }
  #pragma unroll
  for (int off = 1; off < 64; off <<= 1){
    s  += __shfl_xor(s,  off, 64);
    ss += __shfl_xor(ss, off, 64);
  }
  __shared__ float red[8];
  int wid = tid >> 6, lane = tid & 63;
  if (lane == 0){ red[wid] = s; red[4 + wid] = ss; }
  __syncthreads();
  s  = red[0] + red[1] + red[2] + red[3];
  ss = red[4] + red[5] + red[6] + red[7];
  float mu   = s * (1.f / C_);
  float var  = ss * (1.f / C_) - mu * mu;
  float rstd = rsqrtf(var + 1e-5f);
  u16* outr = out + (long)row * C_;
  #pragma unroll
  for (int k = 0; k < 3; ++k){
    int c = tid + k * 256;
    outr[c] = f2bf((v[k] - mu) * rstd * w[c] + bsh[c]);
  }
}

// ------------------------- bf16 NT GEMM (MFMA) -----------------------------
// C[m,n] = alpha * sum_k A[m,k]*B[n,k]  (+bias[n]) (+gelu) (+addsrc[m,n])
// m97 structure: linear LDS [BM][32] u16, global_load_lds dwordx4 staging.
// Block remap: bijective XCD-chunk (8 XCDs), m-fastest within chunk so that
// consecutive blocks on one XCD share the same B panel (L2-resident).
template<int BM, int BN, int WM, int WN, bool GELU>
__global__ __launch_bounds__(256) void gemm_nt(
    const u16* __restrict__ A, const u16* __restrict__ B, float* __restrict__ C,
    const float* __restrict__ bias, const float* __restrict__ addsrc,
    int K, int lda, int ldb, int ldc,
    long batchA, long batchB, long batchC, float alpha)
{
  constexpr int BK = 32;                        // 64 B per LDS row
  __shared__ __align__(16) u16 As[BM * BK];
  __shared__ __align__(16) u16 Bs[BN * BK];
  const int z = blockIdx.z;
  A += (long)z * batchA;
  B += (long)z * batchB;
  float* Cz = C + (long)z * batchC;
  const float* addz = addsrc ? addsrc + (long)z * batchC : nullptr;

  // ---- XCD-chunked bijective remap, m-fastest decomposition ----
  const int gx = gridDim.x, gy = gridDim.y;
  const int nwg = gx * gy;
  int bid = blockIdx.y * gx + blockIdx.x;
  {
    int xcd = bid & 7, pos = bid >> 3;
    int q = nwg >> 3, r = nwg & 7;
    bid = (xcd < r ? xcd * (q + 1) : r * (q + 1) + (xcd - r) * q) + pos;
  }
  const int by = bid % gy;                      // m block (fastest)
  const int bx = bid / gy;                      // n block
  const int n0 = bx * BN, m0 = by * BM;

  const int tid = threadIdx.x, lane = tid & 63, wid = tid >> 6;
  const int l15 = lane & 15, quad = lane >> 4;
  constexpr int WCOLS = BN / WN;
  const int wrow = wid / WCOLS, wcol = wid % WCOLS;
  constexpr int FM = WM / 16, FN = WN / 16;
  f32x4 acc[FM][FN] = {};
  const int ktiles = K / BK;

  // staging geometry: one segment = 16 rows x 32 cols u16 = 1024 B = 64 lanes*16B
  constexpr int SEGA = BM / 16;
  constexpr int SEGB = BN / 16;
  const int srow = lane >> 2;                   // 0..15 row within segment
  const int scol = (lane & 3) * 8;              // 0,8,16,24 col within row

  for (int kt = 0; kt < ktiles; ++kt){
    #pragma unroll
    for (int s = wid; s < SEGA; s += 4)
      gld_lds16(A + (long)(m0 + s * 16 + srow) * lda + kt * BK + scol,
                &As[s * 512]);
    #pragma unroll
    for (int s = wid; s < SEGB; s += 4)
      gld_lds16(B + (long)(n0 + s * 16 + srow) * ldb + kt * BK + scol,
                &Bs[s * 512]);
    __syncthreads();
    bf16x8 af[FM], bfr[FN];
    #pragma unroll
    for (int fm = 0; fm < FM; ++fm)
      af[fm] = *(const bf16x8*)&As[(wrow * WM + fm * 16 + l15) * BK + quad * 8];
    #pragma unroll
    for (int fn = 0; fn < FN; ++fn)
      bfr[fn] = *(const bf16x8*)&Bs[(wcol * WN + fn * 16 + l15) * BK + quad * 8];
    #pragma unroll
    for (int fm = 0; fm < FM; ++fm)
      #pragma unroll
      for (int fn = 0; fn < FN; ++fn)
        acc[fm][fn] = __builtin_amdgcn_mfma_f32_16x16x32_bf16(af[fm], bfr[fn],
                                                              acc[fm][fn], 0, 0, 0);
    __syncthreads();
  }
  #pragma unroll
  for (int fm = 0; fm < FM; ++fm){
    const int rowb = m0 + wrow * WM + fm * 16 + quad * 4;
    #pragma unroll
    for (int fn = 0; fn < FN; ++fn){
      const int col = n0 + wcol * WN + fn * 16 + l15;
      const float bv = bias ? bias[col] : 0.f;
      #pragma unroll
      for (int r = 0; r < 4; ++r){
        float v = acc[fm][fn][r] * alpha + bv;
        if (GELU)
          v = 0.5f * v * (1.f + tanhf(0.7978845608028654f * (v + 0.044715f * v * v * v)));
        const long off = (long)(rowb + r) * ldc + col;
        if (addz) v += addz[off];
        Cz[off] = v;
      }
    }
  }
}

// ---------------- mask: logsigmoid + column cumsum + layer accum -----------
// Block-parallel inclusive scan over queries.
__global__ __launch_bounds__(256) void lp_cumsum(const float* __restrict__ raw,
                                                 const float* __restrict__ int_bias,
                                                 int layer, float* __restrict__ Macc){
  constexpr int CT  = 8;                     // columns per block
  constexpr int RG  = 32;                    // row groups
  constexpr int RPT = T_ / RG;               // rows per thread = 32
  const int tid = threadIdx.x;
  const int c   = tid & (CT - 1);            // column within block
  const int g   = tid >> 3;                  // row group 0..31
  const int gc  = blockIdx.x * CT + c;       // global column 0..2047
  const int b   = gc >> 10;
  const int k   = gc & (T_ - 1);
  const float bias = int_bias[layer];
  const float* rb = raw  + (long)b * T_ * T_;
  float*       Mb = Macc + (long)b * T_ * T_;
  const int q0 = g * RPT;

  float lp[RPT];
  float s = 0.f;
  #pragma unroll
  for (int i = 0; i < RPT; ++i){
    int q = q0 + i;
    float z = rb[(long)q * T_ + k] + bias;
    float v = 0.f;
    if (q > k) v = (z >= -30.f) ? -log1pf(__expf(-z)) : z;
    lp[i] = v;
    s += v;
  }
  __shared__ float sums[RG][CT];
  sums[g][c] = s;
  __syncthreads();
  float run = 0.f;
  for (int g2 = 0; g2 < g; ++g2) run += sums[g2][c];
  #pragma unroll
  for (int i = 0; i < RPT; ++i){
    int q = q0 + i;
    run += lp[i];
    long off = (long)q * T_ + k;
    if (layer == 0) Mb[off] = run;
    else            Mb[off] += run;
  }
}

// -------------- reshape qkv -> head-major q,k (bf16) and v^T (bf16) --------
__global__ __launch_bounds__(256) void reshape_qkv(const float* __restrict__ qkv,
                                                   u16* __restrict__ qb,
                                                   u16* __restrict__ kb,
                                                   u16* __restrict__ vT){
  int row = blockIdx.x;               // b*T + t
  int b = row >> 10, t = row & (T_ - 1);
  const float* src = qkv + (long)row * 2304;
  for (int i = threadIdx.x; i < C_; i += 256){
    int h = i >> 6, d = i & 63;
    long bh = (long)b * H_ + h;
    qb[(bh * T_ + t) * HD_ + d] = f2bf(src[i]);
    kb[(bh * T_ + t) * HD_ + d] = f2bf(src[C_ + i]);
    vT[(bh * HD_ + d) * T_ + t] = f2bf(src[2 * C_ + i]);
  }
}

// --------------------- fused flash attention (bf16 MFMA) -------------------
// grid (T/64, B*H), block 256 (4 waves); wave w owns 16 queries.
__global__ __launch_bounds__(256) void attn_kernel(const u16* __restrict__ qb,
                                                   const u16* __restrict__ kb,
                                                   const u16* __restrict__ vT,
                                                   const float* __restrict__ Macc,
                                                   u16* __restrict__ ybf){
  __shared__ __align__(16) u16 P[4][16 * 72];    // per-wave P tile, padded
  const int qt = blockIdx.x, bh = blockIdx.y;
  const int b = bh / H_, h = bh % H_;
  const int tid = threadIdx.x, wid = tid >> 6, lane = tid & 63;
  const int l15 = lane & 15, quad = lane >> 4;
  const int qbase = qt * 64 + wid * 16;

  const u16* qrow = qb + ((long)bh * T_ + qbase + l15) * HD_;
  bf16x8 aq0 = *(const bf16x8*)(qrow + quad * 8);
  bf16x8 aq1 = *(const bf16x8*)(qrow + 32 + quad * 8);

  float mrow[4], lrow[4];
  f32x4 oacc[4] = {};
  #pragma unroll
  for (int r = 0; r < 4; ++r){ mrow[r] = -1e30f; lrow[r] = 0.f; }

  const float* Mb = Macc + (long)b * T_ * T_;
  const int ntiles = qt + 1;
  for (int kt = 0; kt < ntiles; ++kt){
    // S = Q K^T
    f32x4 s[4];
    #pragma unroll
    for (int fn = 0; fn < 4; ++fn){
      const u16* krow = kb + ((long)bh * T_ + kt * 64 + fn * 16 + l15) * HD_;
      bf16x8 bk0 = *(const bf16x8*)(krow + quad * 8);
      bf16x8 bk1 = *(const bf16x8*)(krow + 32 + quad * 8);
      f32x4 t = {};
      t = __builtin_amdgcn_mfma_f32_16x16x32_bf16(aq0, bk0, t, 0, 0, 0);
      t = __builtin_amdgcn_mfma_f32_16x16x32_bf16(aq1, bk1, t, 0, 0, 0);
      s[fn] = t;
    }
    // scale + additive mask + causal
    float pv[4][4], tmax[4];
    #pragma unroll
    for (int r = 0; r < 4; ++r) tmax[r] = -1e30f;
    #pragma unroll
    for (int fn = 0; fn < 4; ++fn){
      int col = kt * 64 + fn * 16 + l15;
      #pragma unroll
      for (int r = 0; r < 4; ++r){
        int row = qbase + quad * 4 + r;
        float v = (col <= row) ? s[fn][r] * 0.125f + Mb[(long)row * T_ + col]
                               : -1e30f;
        pv[fn][r] = v;
        tmax[r] = fmaxf(tmax[r], v);
      }
    }
    #pragma unroll
    for (int r = 0; r < 4; ++r){
      float v = tmax[r];
      v = fmaxf(v, __shfl_xor(v, 1, 16));
      v = fmaxf(v, __shfl_xor(v, 2, 16));
      v = fmaxf(v, __shfl_xor(v, 4, 16));
      v = fmaxf(v, __shfl_xor(v, 8, 16));
      tmax[r] = v;
    }
    float alp[4], rsum[4];
    #pragma unroll
    for (int r = 0; r < 4; ++r){
      float mnew = fmaxf(mrow[r], tmax[r]);
      alp[r] = __expf(mrow[r] - mnew);
      mrow[r] = mnew;
      rsum[r] = 0.f;
    }
    #pragma unroll
    for (int fn = 0; fn < 4; ++fn)
      #pragma unroll
      for (int r = 0; r < 4; ++r){
        float p = __expf(pv[fn][r] - mrow[r]);
        pv[fn][r] = p;
        rsum[r] += p;
      }
    #pragma unroll
    for (int r = 0; r < 4; ++r){
      float v = rsum[r];
      v += __shfl_xor(v, 1, 16);
      v += __shfl_xor(v, 2, 16);
      v += __shfl_xor(v, 4, 16);
      v += __shfl_xor(v, 8, 16);
      lrow[r] = lrow[r] * alp[r] + v;
    }
    // P (C-layout) -> LDS -> A-layout; rescale O
    #pragma unroll
    for (int fn = 0; fn < 4; ++fn)
      #pragma unroll
      for (int r = 0; r < 4; ++r)
        P[wid][(quad * 4 + r) * 72 + fn * 16 + l15] = f2bf(pv[fn][r]);
    #pragma unroll
    for (int fn = 0; fn < 4; ++fn)
      #pragma unroll
      for (int r = 0; r < 4; ++r)
        oacc[fn][r] *= alp[r];
    bf16x8 ap0 = *(const bf16x8*)&P[wid][l15 * 72 + quad * 8];
    bf16x8 ap1 = *(const bf16x8*)&P[wid][l15 * 72 + 32 + quad * 8];
    #pragma unroll
    for (int fn = 0; fn < 4; ++fn){
      const u16* vrow = vT + ((long)bh * HD_ + fn * 16 + l15) * T_ + kt * 64;
      bf16x8 bv0 = *(const bf16x8*)(vrow + quad * 8);
      bf16x8 bv1 = *(const bf16x8*)(vrow + 32 + quad * 8);
      oacc[fn] = __builtin_amdgcn_mfma_f32_16x16x32_bf16(ap0, bv0, oacc[fn], 0, 0, 0);
      oacc[fn] = __builtin_amdgcn_mfma_f32_16x16x32_bf16(ap1, bv1, oacc[fn], 0, 0, 0);
    }
  }
  #pragma unroll
  for (int fn = 0; fn < 4; ++fn)
    #pragma unroll
    for (int r = 0; r < 4; ++r){
      int row = qbase + quad * 4 + r;
      int d   = fn * 16 + l15;
      float o = oacc[fn][r] / lrow[r];
      ybf[((long)b * T_ + row) * C_ + h * HD_ + d] = f2bf(o);
    }
}

// ---------------------------------------------------------------------------
extern "C" void kernel_launch(void* const* d_in, const int* in_sizes, int n_in,
                              void* d_out, int out_size, void* d_ws, size_t ws_size,
                              hipStream_t stream)
{
  (void)in_sizes; (void)n_in; (void)out_size; (void)ws_size;
  const float* wte     = (const float*)d_in[0];
  const float* wpe     = (const float*)d_in[1];
  const float* ln1_w   = (const float*)d_in[2];
  const float* ln1_b   = (const float*)d_in[3];
  const float* attn_w  = (const float*)d_in[4];
  const float* attn_b  = (const float*)d_in[5];
  const float* qint_w  = (const float*)d_in[6];
  const float* kint_w  = (const float*)d_in[7];
  const float* int_bias= (const float*)d_in[8];
  const float* proj_w  = (const float*)d_in[9];
  const float* proj_b  = (const float*)d_in[10];
  const float* ln2_w   = (const float*)d_in[11];
  const float* ln2_b   = (const float*)d_in[12];
  const float* fc_w    = (const float*)d_in[13];
  const float* fc_b    = (const float*)d_in[14];
  const float* fc2_w   = (const float*)d_in[15];
  const float* fc2_b   = (const float*)d_in[16];
  const float* lnf_w   = (const float*)d_in[17];
  const float* lnf_b   = (const float*)d_in[18];
  const int*   idx     = (const int*)d_in[19];
  float* out = (float*)d_out;

  char* p = (char*)d_ws;
  auto alloc = [&](long bytes) -> char* {
    char* r = p; p += (bytes + 255) & ~255L; return r;
  };
  u16*   wte_bf   = (u16*)  alloc((long)V_ * C_ * 2);
  u16*   attnw_bf = (u16*)  alloc((long)L_ * 3 * C_ * C_ * 2);
  u16*   wint_bf  = (u16*)  alloc((long)L_ * 128 * C_ * 2);
  u16*   projw_bf = (u16*)  alloc((long)L_ * C_ * C_ * 2);
  u16*   fcw_bf   = (u16*)  alloc((long)L_ * 4 * C_ * C_ * 2);
  u16*   fc2w_bf  = (u16*)  alloc((long)L_ * C_ * 4 * C_ * 2);
  float* x        = (float*)alloc((long)B_ * T_ * C_ * 4);
  u16*   hbf      = (u16*)  alloc((long)B_ * T_ * C_ * 2);
  float* qkv      = (float*)alloc((long)B_ * T_ * 3 * C_ * 4);
  float* qkint    = (float*)alloc((long)B_ * T_ * 128 * 4);
  u16*   qkintbf  = (u16*)  alloc((long)B_ * T_ * 128 * 2);
  float* raw      = (float*)alloc((long)B_ * T_ * T_ * 4);
  float* Macc     = (float*)alloc((long)B_ * T_ * T_ * 4);
  u16*   qb       = (u16*)  alloc((long)B_ * H_ * T_ * HD_ * 2);
  u16*   kb       = (u16*)  alloc((long)B_ * H_ * T_ * HD_ * 2);
  u16*   vT       = (u16*)  alloc((long)B_ * H_ * T_ * HD_ * 2);
  u16*   ybf      = (u16*)  alloc((long)B_ * T_ * C_ * 2);
  float* ff       = (float*)alloc((long)B_ * T_ * 4 * C_ * 4);
  u16*   ffbf     = (u16*)  alloc((long)B_ * T_ * 4 * C_ * 2);

  auto conv = [&](const float* s, u16* d, long n){
    f2bf_vec<<<(int)(n / 1024), 256, 0, stream>>>((const float4*)s, (ushort4*)d);
  };
  // weights -> bf16 (ws is re-poisoned before every call; must redo each time)
  conv(wte,    wte_bf,   (long)V_ * C_);
  conv(attn_w, attnw_bf, (long)L_ * 3 * C_ * C_);
  conv(proj_w, projw_bf, (long)L_ * C_ * C_);
  conv(fc_w,   fcw_bf,   (long)L_ * 4 * C_ * C_);
  conv(fc2_w,  fc2w_bf,  (long)L_ * C_ * 4 * C_);
  build_wint<<<(L_ * 128 * C_) / 256, 256, 0, stream>>>(qint_w, kint_w, wint_bf);

  embed_kernel<<<B_ * T_, 256, 0, stream>>>(wte, wpe, idx, x);

  const int M = B_ * T_;   // 2048
  for (int l = 0; l < L_; ++l){
    // ln1 -> h
    layernorm_bf16<<<M, 256, 0, stream>>>(x, ln1_w + l * C_, ln1_b + l * C_, hbf);
    // qkv = h @ attn_w^T + b
    gemm_nt<128,128,64,64,false><<<dim3(2304/128, M/128), 256, 0, stream>>>(
        hbf, attnw_bf + (long)l * 3 * C_ * C_, qkv, attn_b + l * 3 * C_, nullptr,
        C_, C_, C_, 3 * C_, 0, 0, 0, 1.f);
    // [q_int | k_int] = h @ wint^T
    gemm_nt<64,64,32,32,false><<<dim3(128/64, M/64), 256, 0, stream>>>(
        hbf, wint_bf + (long)l * 128 * C_, qkint, nullptr, nullptr,
        C_, C_, C_, 128, 0, 0, 0, 1.f);
    conv(qkint, qkintbf, (long)M * 128);
    // raw = q_int @ k_int^T / 8   (batched over B)
    gemm_nt<128,128,64,64,false><<<dim3(T_/128, T_/128, B_), 256, 0, stream>>>(
        qkintbf, qkintbf + 64, raw, nullptr, nullptr,
        64, 128, 128, T_, (long)T_ * 128, (long)T_ * 128, (long)T_ * T_, 0.125f);
    // mask: block-parallel scan of logsigmoid(raw+bias), accum across layers
    lp_cumsum<<<(B_ * T_) / 8, 256, 0, stream>>>(raw, int_bias, l, Macc);
    // attention
    reshape_qkv<<<M, 256, 0, stream>>>(qkv, qb, kb, vT);
    attn_kernel<<<dim3(T_/64, B_ * H_), 256, 0, stream>>>(qb, kb, vT, Macc, ybf);
    // x += y @ proj_w^T + b
    gemm_nt<128,128,64,64,false><<<dim3(C_/128, M/128), 256, 0, stream>>>(
        ybf, projw_bf + (long)l * C_ * C_, x, proj_b + l * C_, x,
        C_, C_, C_, C_, 0, 0, 0, 1.f);
    // ln2 -> h2
    layernorm_bf16<<<M, 256, 0, stream>>>(x, ln2_w + l * C_, ln2_b + l * C_, hbf);
    // ff = gelu(h2 @ fc_w^T + b)
    gemm_nt<128,128,64,64,true><<<dim3(4*C_/128, M/128), 256, 0, stream>>>(
        hbf, fcw_bf + (long)l * 4 * C_ * C_, ff, fc_b + l * 4 * C_, nullptr,
        C_, C_, C_, 4 * C_, 0, 0, 0, 1.f);
    conv(ff, ffbf, (long)M * 4 * C_);
    // x += ff @ fc2_w^T + b
    gemm_nt<128,128,64,64,false><<<dim3(C_/128, M/128), 256, 0, stream>>>(
        ffbf, fc2w_bf + (long)l * C_ * 4 * C_, x, fc2_b + l * C_, x,
        4 * C_, 4 * C_, 4 * C_, C_, 0, 0, 0, 1.f);
  }
  // final LN + weight-tied lm_head
  layernorm_bf16<<<M, 256, 0, stream>>>(x, lnf_w, lnf_b, hbf);
  gemm_nt<128,128,64,64,false><<<dim3(V_/128, M/128), 256, 0, stream>>>(
      hbf, wte_bf, out, nullptr, nullptr,
      C_, C_, C_, V_, 0, 0, 0, 1.f);
}

// Round 3
// 1986.121 us; speedup vs baseline: 2.7845x; 1.1567x over previous
//
#include <hip/hip_runtime.h>

// ---------------------------------------------------------------------------
// GPT forward (B=2,T=1024,C=768,H=12,hd=64,L=4,V=50304,DINT=64) on gfx950.
// entmax(alpha=1+1e-6) over [raw,0] == sigmoid(raw) to ~1e-5 (see analysis).
// All GEMMs: bf16 MFMA 16x16x32, f32 accumulate.
// GEMM: global_load_lds dwordx4 staging, double-buffered LDS, counted-vmcnt
// prefetch (raw s_barrier, never vmcnt(0) mid-loop), XCD-chunked remap.
// ---------------------------------------------------------------------------

using f32x4  = __attribute__((ext_vector_type(4))) float;
using bf16x8 = __attribute__((ext_vector_type(8))) __bf16;
typedef unsigned short u16;
typedef unsigned int   u32;

#define B_  2
#define T_  1024
#define C_  768
#define H_  12
#define HD_ 64
#define L_  4
#define V_  50304

__device__ __forceinline__ u16 f2bf(float f){
  u32 u = __float_as_uint(f);
  u += 0x7fffu + ((u >> 16) & 1u);       // RNE to bf16
  return (u16)(u >> 16);
}

// async global->LDS, 16 bytes per lane. ldsbase must be wave-uniform;
// HW writes ldsbase + lane*16. gsrc is per-lane.
__device__ __forceinline__ void gld_lds16(const u16* gsrc, u16* ldsbase){
  __builtin_amdgcn_global_load_lds(
      (const __attribute__((address_space(1))) void*)gsrc,
      (__attribute__((address_space(3))) void*)ldsbase, 16, 0, 0);
}

// -------------------------- weight / tensor converts -----------------------
__global__ __launch_bounds__(256) void f2bf_vec(const float4* __restrict__ src,
                                                ushort4* __restrict__ dst){
  long i = (long)blockIdx.x * 256 + threadIdx.x;
  float4 v = src[i];
  ushort4 o;
  o.x = f2bf(v.x); o.y = f2bf(v.y); o.z = f2bf(v.z); o.w = f2bf(v.w);
  dst[i] = o;
}

// interleave qint_w / kint_w -> wint[l][128][768] bf16 (rows 0-63 q, 64-127 k)
__global__ __launch_bounds__(256) void build_wint(const float* __restrict__ qint_w,
                                                  const float* __restrict__ kint_w,
                                                  u16* __restrict__ wint){
  long i = (long)blockIdx.x * 256 + threadIdx.x;   // < 4*128*768
  int c  = (int)(i % 768);
  long r = i / 768;
  int rr = (int)(r & 127);
  int l  = (int)(r >> 7);
  const float* src = (rr < 64) ? qint_w : kint_w;
  wint[i] = f2bf(src[((long)l * 64 + (rr & 63)) * 768 + c]);
}

// ------------------------------- embedding ---------------------------------
__global__ __launch_bounds__(256) void embed_kernel(const float* __restrict__ wte,
                                                    const float* __restrict__ wpe,
                                                    const int* __restrict__ idx,
                                                    float* __restrict__ x){
  int row = blockIdx.x;              // b*T + t
  int t   = row & (T_ - 1);
  int id  = idx[row];
  const float* ws = wte + (long)id * C_;
  const float* ps = wpe + (long)t  * C_;
  float* xr = x + (long)row * C_;
  for (int c = threadIdx.x; c < C_; c += 256) xr[c] = ws[c] + ps[c];
}

// ------------------------------- layernorm ---------------------------------
__global__ __launch_bounds__(256) void layernorm_bf16(const float* __restrict__ x,
                                                      const float* __restrict__ w,
                                                      const float* __restrict__ bsh,
                                                      u16* __restrict__ out){
  int row = blockIdx.x;
  const float* xr = x + (long)row * C_;
  int tid = threadIdx.x;
  float v[3], s = 0.f, ss = 0.f;
  #pragma unroll
  for (int k = 0; k < 3; ++k){
    float t = xr[tid + k * 256];
    v[k] = t; s += t; ss += t * t;
  }
  #pragma unroll
  for (int off = 1; off < 64; off <<= 1){
    s  += __shfl_xor(s,  off, 64);
    ss += __shfl_xor(ss, off, 64);
  }
  __shared__ float red[8];
  int wid = tid >> 6, lane = tid & 63;
  if (lane == 0){ red[wid] = s; red[4 + wid] = ss; }
  __syncthreads();
  s  = red[0] + red[1] + red[2] + red[3];
  ss = red[4] + red[5] + red[6] + red[7];
  float mu   = s * (1.f / C_);
  float var  = ss * (1.f / C_) - mu * mu;
  float rstd = rsqrtf(var + 1e-5f);
  u16* outr = out + (long)row * C_;
  #pragma unroll
  for (int k = 0; k < 3; ++k){
    int c = tid + k * 256;
    outr[c] = f2bf((v[k] - mu) * rstd * w[c] + bsh[c]);
  }
}

// ------------------------- bf16 NT GEMM (MFMA) -----------------------------
// C[m,n] = alpha * sum_k A[m,k]*B[n,k]  (+bias[n]) (+gelu) (+addsrc[m,n])
// OMODE: 0 = f32 output, 1 = bf16 (u16) output.
// Double-buffered LDS, prefetch next K-tile, counted vmcnt (never 0 in loop),
// raw s_barrier + sched_barrier pins. XCD-chunked bijective remap, m-fastest.
template<int BM, int BN, int WM, int WN, bool GELU, int OMODE>
__global__ __launch_bounds__(256) void gemm_nt(
    const u16* __restrict__ A, const u16* __restrict__ B, void* __restrict__ Cv,
    const float* __restrict__ bias, const float* __restrict__ addsrc,
    int K, int lda, int ldb, int ldc,
    long batchA, long batchB, long batchC, float alpha)
{
  constexpr int BK = 32;                        // 64 B per LDS row
  constexpr int TILEA = BM * BK, TILEB = BN * BK;
  __shared__ __align__(16) u16 As[2 * TILEA];
  __shared__ __align__(16) u16 Bs[2 * TILEB];
  const int z = blockIdx.z;
  A += (long)z * batchA;
  B += (long)z * batchB;

  // ---- XCD-chunked bijective remap, m-fastest decomposition ----
  const int gx = gridDim.x, gy = gridDim.y;
  const int nwg = gx * gy;
  int bid = blockIdx.y * gx + blockIdx.x;
  {
    int xcd = bid & 7, pos = bid >> 3;
    int q = nwg >> 3, r = nwg & 7;
    bid = (xcd < r ? xcd * (q + 1) : r * (q + 1) + (xcd - r) * q) + pos;
  }
  const int by = bid % gy;                      // m block (fastest)
  const int bx = bid / gy;                      // n block
  const int n0 = bx * BN, m0 = by * BM;

  const int tid = threadIdx.x, lane = tid & 63, wid = tid >> 6;
  const int l15 = lane & 15, quad = lane >> 4;
  constexpr int WCOLS = BN / WN;
  const int wrow = wid / WCOLS, wcol = wid % WCOLS;
  constexpr int FM = WM / 16, FN = WN / 16;
  f32x4 acc[FM][FN] = {};
  const int ktiles = K / BK;

  // staging geometry: one segment = 16 rows x 32 cols u16 = 1024 B = 64 lanes*16B
  constexpr int SEGA = BM / 16;
  constexpr int SEGB = BN / 16;
  constexpr int NLD = SEGA / 4 + SEGB / 4;      // per-lane loads per K-tile
  const int srow = lane >> 2;                   // 0..15 row within segment
  const int scol = (lane & 3) * 8;              // 0,8,16,24 col within row

  auto stage = [&](int kt, int buf){
    #pragma unroll
    for (int s = wid; s < SEGA; s += 4)
      gld_lds16(A + (long)(m0 + s * 16 + srow) * lda + kt * BK + scol,
                &As[buf * TILEA + s * 512]);
    #pragma unroll
    for (int s = wid; s < SEGB; s += 4)
      gld_lds16(B + (long)(n0 + s * 16 + srow) * ldb + kt * BK + scol,
                &Bs[buf * TILEB + s * 512]);
  };

  stage(0, 0);
  for (int kt = 0; kt < ktiles; ++kt){
    const int cur = kt & 1;
    if (kt + 1 < ktiles){
      stage(kt + 1, cur ^ 1);
      asm volatile("s_waitcnt vmcnt(%0)" :: "i"(NLD) : "memory");
    } else {
      asm volatile("s_waitcnt vmcnt(0)" ::: "memory");
    }
    __builtin_amdgcn_s_barrier();
    __builtin_amdgcn_sched_barrier(0);
    bf16x8 af[FM], bfr[FN];
    #pragma unroll
    for (int fm = 0; fm < FM; ++fm)
      af[fm] = *(const bf16x8*)&As[cur * TILEA +
                                   (wrow * WM + fm * 16 + l15) * BK + quad * 8];
    #pragma unroll
    for (int fn = 0; fn < FN; ++fn)
      bfr[fn] = *(const bf16x8*)&Bs[cur * TILEB +
                                    (wcol * WN + fn * 16 + l15) * BK + quad * 8];
    #pragma unroll
    for (int fm = 0; fm < FM; ++fm)
      #pragma unroll
      for (int fn = 0; fn < FN; ++fn)
        acc[fm][fn] = __builtin_amdgcn_mfma_f32_16x16x32_bf16(af[fm], bfr[fn],
                                                              acc[fm][fn], 0, 0, 0);
    __builtin_amdgcn_sched_barrier(0);
    __builtin_amdgcn_s_barrier();
    __builtin_amdgcn_sched_barrier(0);
  }

  #pragma unroll
  for (int fm = 0; fm < FM; ++fm){
    const int rowb = m0 + wrow * WM + fm * 16 + quad * 4;
    #pragma unroll
    for (int fn = 0; fn < FN; ++fn){
      const int col = n0 + wcol * WN + fn * 16 + l15;
      const float bv = bias ? bias[col] : 0.f;
      #pragma unroll
      for (int r = 0; r < 4; ++r){
        float v = acc[fm][fn][r] * alpha + bv;
        if (GELU)
          v = 0.5f * v * (1.f + tanhf(0.7978845608028654f * (v + 0.044715f * v * v * v)));
        const long off = (long)(rowb + r) * ldc + col;
        if (OMODE == 0){
          float* Cz = (float*)Cv + (long)z * batchC;
          if (addsrc) v += addsrc[(long)z * batchC + off];
          Cz[off] = v;
        } else {
          u16* Cz = (u16*)Cv + (long)z * batchC;
          Cz[off] = f2bf(v);
        }
      }
    }
  }
}

// ---------------- mask: logsigmoid + column cumsum + layer accum -----------
// Block-parallel inclusive scan over queries.
__global__ __launch_bounds__(256) void lp_cumsum(const float* __restrict__ raw,
                                                 const float* __restrict__ int_bias,
                                                 int layer, float* __restrict__ Macc){
  constexpr int CT  = 8;                     // columns per block
  constexpr int RG  = 32;                    // row groups
  constexpr int RPT = T_ / RG;               // rows per thread = 32
  const int tid = threadIdx.x;
  const int c   = tid & (CT - 1);            // column within block
  const int g   = tid >> 3;                  // row group 0..31
  const int gc  = blockIdx.x * CT + c;       // global column 0..2047
  const int b   = gc >> 10;
  const int k   = gc & (T_ - 1);
  const float bias = int_bias[layer];
  const float* rb = raw  + (long)b * T_ * T_;
  float*       Mb = Macc + (long)b * T_ * T_;
  const int q0 = g * RPT;

  float lp[RPT];
  float s = 0.f;
  #pragma unroll
  for (int i = 0; i < RPT; ++i){
    int q = q0 + i;
    float z = rb[(long)q * T_ + k] + bias;
    float v = 0.f;
    if (q > k) v = (z >= -30.f) ? -log1pf(__expf(-z)) : z;
    lp[i] = v;
    s += v;
  }
  __shared__ float sums[RG][CT];
  sums[g][c] = s;
  __syncthreads();
  float run = 0.f;
  for (int g2 = 0; g2 < g; ++g2) run += sums[g2][c];
  #pragma unroll
  for (int i = 0; i < RPT; ++i){
    int q = q0 + i;
    run += lp[i];
    long off = (long)q * T_ + k;
    if (layer == 0) Mb[off] = run;
    else            Mb[off] += run;
  }
}

// -------------- reshape qkv(bf16) -> head-major q,k (copy only) ------------
__global__ __launch_bounds__(256) void reshape_qk(const u16* __restrict__ qkv,
                                                  u16* __restrict__ qb,
                                                  u16* __restrict__ kb){
  int row = blockIdx.x;               // b*T + t
  int b = row >> 10, t = row & (T_ - 1);
  const u16* src = qkv + (long)row * 2304;
  for (int i = threadIdx.x; i < C_; i += 256){
    int h = i >> 6, d = i & 63;
    long bh = (long)b * H_ + h;
    qb[(bh * T_ + t) * HD_ + d] = src[i];
    kb[(bh * T_ + t) * HD_ + d] = src[C_ + i];
  }
}

// ----- v slice of qkv(bf16) -> vT[bh][d][t] via LDS transpose (coalesced) ---
__global__ __launch_bounds__(256) void transpose_v(const u16* __restrict__ qkv,
                                                   u16* __restrict__ vT){
  __shared__ u16 tile[64][65];        // [d][t], +1 pad
  const int bh = blockIdx.x;
  const int b = bh / H_, h = bh % H_;
  const int t0 = blockIdx.y * 64;
  const int tid = threadIdx.x;
  const int tl = tid >> 6;            // 0..3
  const int dl = tid & 63;            // d
  #pragma unroll
  for (int i = 0; i < 16; ++i){
    int t = t0 + tl * 16 + i;
    tile[dl][tl * 16 + i] = qkv[(long)(b * T_ + t) * 2304 + 2 * C_ + h * 64 + dl];
  }
  __syncthreads();
  const int dr = tid >> 2;            // 0..63
  const int tc = (tid & 3) * 16;      // 0,16,32,48
  u16* dst = vT + ((long)bh * HD_ + dr) * T_ + t0 + tc;
  #pragma unroll
  for (int c = 0; c < 16; c += 4){
    ushort4 o;
    o.x = tile[dr][tc + c];     o.y = tile[dr][tc + c + 1];
    o.z = tile[dr][tc + c + 2]; o.w = tile[dr][tc + c + 3];
    *(ushort4*)(dst + c) = o;
  }
}

// --------------------- fused flash attention (bf16 MFMA) -------------------
// grid (T/64, B*H), block 256 (4 waves); wave w owns 16 queries.
__global__ __launch_bounds__(256) void attn_kernel(const u16* __restrict__ qb,
                                                   const u16* __restrict__ kb,
                                                   const u16* __restrict__ vT,
                                                   const float* __restrict__ Macc,
                                                   u16* __restrict__ ybf){
  __shared__ __align__(16) u16 P[4][16 * 72];    // per-wave P tile, padded
  const int qt = blockIdx.x, bh = blockIdx.y;
  const int b = bh / H_, h = bh % H_;
  const int tid = threadIdx.x, wid = tid >> 6, lane = tid & 63;
  const int l15 = lane & 15, quad = lane >> 4;
  const int qbase = qt * 64 + wid * 16;

  const u16* qrow = qb + ((long)bh * T_ + qbase + l15) * HD_;
  bf16x8 aq0 = *(const bf16x8*)(qrow + quad * 8);
  bf16x8 aq1 = *(const bf16x8*)(qrow + 32 + quad * 8);

  float mrow[4], lrow[4];
  f32x4 oacc[4] = {};
  #pragma unroll
  for (int r = 0; r < 4; ++r){ mrow[r] = -1e30f; lrow[r] = 0.f; }

  const float* Mb = Macc + (long)b * T_ * T_;
  const int ntiles = qt + 1;
  for (int kt = 0; kt < ntiles; ++kt){
    // S = Q K^T
    f32x4 s[4];
    #pragma unroll
    for (int fn = 0; fn < 4; ++fn){
      const u16* krow = kb + ((long)bh * T_ + kt * 64 + fn * 16 + l15) * HD_;
      bf16x8 bk0 = *(const bf16x8*)(krow + quad * 8);
      bf16x8 bk1 = *(const bf16x8*)(krow + 32 + quad * 8);
      f32x4 t = {};
      t = __builtin_amdgcn_mfma_f32_16x16x32_bf16(aq0, bk0, t, 0, 0, 0);
      t = __builtin_amdgcn_mfma_f32_16x16x32_bf16(aq1, bk1, t, 0, 0, 0);
      s[fn] = t;
    }
    // scale + additive mask + causal
    float pv[4][4], tmax[4];
    #pragma unroll
    for (int r = 0; r < 4; ++r) tmax[r] = -1e30f;
    #pragma unroll
    for (int fn = 0; fn < 4; ++fn){
      int col = kt * 64 + fn * 16 + l15;
      #pragma unroll
      for (int r = 0; r < 4; ++r){
        int row = qbase + quad * 4 + r;
        float v = (col <= row) ? s[fn][r] * 0.125f + Mb[(long)row * T_ + col]
                               : -1e30f;
        pv[fn][r] = v;
        tmax[r] = fmaxf(tmax[r], v);
      }
    }
    #pragma unroll
    for (int r = 0; r < 4; ++r){
      float v = tmax[r];
      v = fmaxf(v, __shfl_xor(v, 1, 16));
      v = fmaxf(v, __shfl_xor(v, 2, 16));
      v = fmaxf(v, __shfl_xor(v, 4, 16));
      v = fmaxf(v, __shfl_xor(v, 8, 16));
      tmax[r] = v;
    }
    float alp[4], rsum[4];
    #pragma unroll
    for (int r = 0; r < 4; ++r){
      float mnew = fmaxf(mrow[r], tmax[r]);
      alp[r] = __expf(mrow[r] - mnew);
      mrow[r] = mnew;
      rsum[r] = 0.f;
    }
    #pragma unroll
    for (int fn = 0; fn < 4; ++fn)
      #pragma unroll
      for (int r = 0; r < 4; ++r){
        float p = __expf(pv[fn][r] - mrow[r]);
        pv[fn][r] = p;
        rsum[r] += p;
      }
    #pragma unroll
    for (int r = 0; r < 4; ++r){
      float v = rsum[r];
      v += __shfl_xor(v, 1, 16);
      v += __shfl_xor(v, 2, 16);
      v += __shfl_xor(v, 4, 16);
      v += __shfl_xor(v, 8, 16);
      lrow[r] = lrow[r] * alp[r] + v;
    }
    // P (C-layout) -> LDS -> A-layout; rescale O
    #pragma unroll
    for (int fn = 0; fn < 4; ++fn)
      #pragma unroll
      for (int r = 0; r < 4; ++r)
        P[wid][(quad * 4 + r) * 72 + fn * 16 + l15] = f2bf(pv[fn][r]);
    #pragma unroll
    for (int fn = 0; fn < 4; ++fn)
      #pragma unroll
      for (int r = 0; r < 4; ++r)
        oacc[fn][r] *= alp[r];
    bf16x8 ap0 = *(const bf16x8*)&P[wid][l15 * 72 + quad * 8];
    bf16x8 ap1 = *(const bf16x8*)&P[wid][l15 * 72 + 32 + quad * 8];
    #pragma unroll
    for (int fn = 0; fn < 4; ++fn){
      const u16* vrow = vT + ((long)bh * HD_ + fn * 16 + l15) * T_ + kt * 64;
      bf16x8 bv0 = *(const bf16x8*)(vrow + quad * 8);
      bf16x8 bv1 = *(const bf16x8*)(vrow + 32 + quad * 8);
      oacc[fn] = __builtin_amdgcn_mfma_f32_16x16x32_bf16(ap0, bv0, oacc[fn], 0, 0, 0);
      oacc[fn] = __builtin_amdgcn_mfma_f32_16x16x32_bf16(ap1, bv1, oacc[fn], 0, 0, 0);
    }
  }
  #pragma unroll
  for (int fn = 0; fn < 4; ++fn)
    #pragma unroll
    for (int r = 0; r < 4; ++r){
      int row = qbase + quad * 4 + r;
      int d   = fn * 16 + l15;
      float o = oacc[fn][r] / lrow[r];
      ybf[((long)b * T_ + row) * C_ + h * HD_ + d] = f2bf(o);
    }
}

// ---------------------------------------------------------------------------
extern "C" void kernel_launch(void* const* d_in, const int* in_sizes, int n_in,
                              void* d_out, int out_size, void* d_ws, size_t ws_size,
                              hipStream_t stream)
{
  (void)in_sizes; (void)n_in; (void)out_size; (void)ws_size;
  const float* wte     = (const float*)d_in[0];
  const float* wpe     = (const float*)d_in[1];
  const float* ln1_w   = (const float*)d_in[2];
  const float* ln1_b   = (const float*)d_in[3];
  const float* attn_w  = (const float*)d_in[4];
  const float* attn_b  = (const float*)d_in[5];
  const float* qint_w  = (const float*)d_in[6];
  const float* kint_w  = (const float*)d_in[7];
  const float* int_bias= (const float*)d_in[8];
  const float* proj_w  = (const float*)d_in[9];
  const float* proj_b  = (const float*)d_in[10];
  const float* ln2_w   = (const float*)d_in[11];
  const float* ln2_b   = (const float*)d_in[12];
  const float* fc_w    = (const float*)d_in[13];
  const float* fc_b    = (const float*)d_in[14];
  const float* fc2_w   = (const float*)d_in[15];
  const float* fc2_b   = (const float*)d_in[16];
  const float* lnf_w   = (const float*)d_in[17];
  const float* lnf_b   = (const float*)d_in[18];
  const int*   idx     = (const int*)d_in[19];
  float* out = (float*)d_out;

  char* p = (char*)d_ws;
  auto alloc = [&](long bytes) -> char* {
    char* r = p; p += (bytes + 255) & ~255L; return r;
  };
  u16*   wte_bf   = (u16*)  alloc((long)V_ * C_ * 2);
  u16*   attnw_bf = (u16*)  alloc((long)L_ * 3 * C_ * C_ * 2);
  u16*   wint_bf  = (u16*)  alloc((long)L_ * 128 * C_ * 2);
  u16*   projw_bf = (u16*)  alloc((long)L_ * C_ * C_ * 2);
  u16*   fcw_bf   = (u16*)  alloc((long)L_ * 4 * C_ * C_ * 2);
  u16*   fc2w_bf  = (u16*)  alloc((long)L_ * C_ * 4 * C_ * 2);
  float* x        = (float*)alloc((long)B_ * T_ * C_ * 4);
  u16*   hbf      = (u16*)  alloc((long)B_ * T_ * C_ * 2);
  u16*   qkv      = (u16*)  alloc((long)B_ * T_ * 3 * C_ * 2);   // bf16
  u16*   qkintbf  = (u16*)  alloc((long)B_ * T_ * 128 * 2);
  float* raw      = (float*)alloc((long)B_ * T_ * T_ * 4);
  float* Macc     = (float*)alloc((long)B_ * T_ * T_ * 4);
  u16*   qb       = (u16*)  alloc((long)B_ * H_ * T_ * HD_ * 2);
  u16*   kb       = (u16*)  alloc((long)B_ * H_ * T_ * HD_ * 2);
  u16*   vT       = (u16*)  alloc((long)B_ * H_ * T_ * HD_ * 2);
  u16*   ybf      = (u16*)  alloc((long)B_ * T_ * C_ * 2);
  u16*   ffbf     = (u16*)  alloc((long)B_ * T_ * 4 * C_ * 2);

  auto conv = [&](const float* s, u16* d, long n){
    f2bf_vec<<<(int)(n / 1024), 256, 0, stream>>>((const float4*)s, (ushort4*)d);
  };
  // weights -> bf16 (ws is re-poisoned before every call; must redo each time)
  conv(wte,    wte_bf,   (long)V_ * C_);
  conv(attn_w, attnw_bf, (long)L_ * 3 * C_ * C_);
  conv(proj_w, projw_bf, (long)L_ * C_ * C_);
  conv(fc_w,   fcw_bf,   (long)L_ * 4 * C_ * C_);
  conv(fc2_w,  fc2w_bf,  (long)L_ * C_ * 4 * C_);
  build_wint<<<(L_ * 128 * C_) / 256, 256, 0, stream>>>(qint_w, kint_w, wint_bf);

  embed_kernel<<<B_ * T_, 256, 0, stream>>>(wte, wpe, idx, x);

  const int M = B_ * T_;   // 2048
  for (int l = 0; l < L_; ++l){
    // ln1 -> h
    layernorm_bf16<<<M, 256, 0, stream>>>(x, ln1_w + l * C_, ln1_b + l * C_, hbf);
    // qkv = h @ attn_w^T + b   (bf16 out)
    gemm_nt<128,128,64,64,false,1><<<dim3(2304/128, M/128), 256, 0, stream>>>(
        hbf, attnw_bf + (long)l * 3 * C_ * C_, qkv, attn_b + l * 3 * C_, nullptr,
        C_, C_, C_, 3 * C_, 0, 0, 0, 1.f);
    // [q_int | k_int] = h @ wint^T   (bf16 out)
    gemm_nt<64,64,32,32,false,1><<<dim3(128/64, M/64), 256, 0, stream>>>(
        hbf, wint_bf + (long)l * 128 * C_, qkintbf, nullptr, nullptr,
        C_, C_, C_, 128, 0, 0, 0, 1.f);
    // raw = q_int @ k_int^T / 8   (batched over B, f32 out)
    gemm_nt<128,128,64,64,false,0><<<dim3(T_/128, T_/128, B_), 256, 0, stream>>>(
        qkintbf, qkintbf + 64, raw, nullptr, nullptr,
        64, 128, 128, T_, (long)T_ * 128, (long)T_ * 128, (long)T_ * T_, 0.125f);
    // mask: block-parallel scan of logsigmoid(raw+bias), accum across layers
    lp_cumsum<<<(B_ * T_) / 8, 256, 0, stream>>>(raw, int_bias, l, Macc);
    // attention
    reshape_qk<<<M, 256, 0, stream>>>(qkv, qb, kb);
    transpose_v<<<dim3(B_ * H_, T_ / 64), 256, 0, stream>>>(qkv, vT);
    attn_kernel<<<dim3(T_/64, B_ * H_), 256, 0, stream>>>(qb, kb, vT, Macc, ybf);
    // x += y @ proj_w^T + b
    gemm_nt<128,128,64,64,false,0><<<dim3(C_/128, M/128), 256, 0, stream>>>(
        ybf, projw_bf + (long)l * C_ * C_, x, proj_b + l * C_, x,
        C_, C_, C_, C_, 0, 0, 0, 1.f);
    // ln2 -> h2
    layernorm_bf16<<<M, 256, 0, stream>>>(x, ln2_w + l * C_, ln2_b + l * C_, hbf);
    // ffbf = gelu(h2 @ fc_w^T + b)   (bf16 out, conv fused)
    gemm_nt<128,128,64,64,true,1><<<dim3(4*C_/128, M/128), 256, 0, stream>>>(
        hbf, fcw_bf + (long)l * 4 * C_ * C_, ffbf, fc_b + l * 4 * C_, nullptr,
        C_, C_, C_, 4 * C_, 0, 0, 0, 1.f);
    // x += ff @ fc2_w^T + b
    gemm_nt<128,128,64,64,false,0><<<dim3(C_/128, M/128), 256, 0, stream>>>(
        ffbf, fc2w_bf + (long)l * C_ * 4 * C_, x, fc2_b + l * C_, x,
        4 * C_, 4 * C_, 4 * C_, C_, 0, 0, 0, 1.f);
  }
  // final LN + weight-tied lm_head
  layernorm_bf16<<<M, 256, 0, stream>>>(x, lnf_w, lnf_b, hbf);
  gemm_nt<128,128,64,64,false,0><<<dim3(V_/128, M/128), 256, 0, stream>>>(
      hbf, wte_bf, out, nullptr, nullptr,
      C_, C_, C_, V_, 0, 0, 0, 1.f);
}